// Round 21
// baseline (259.821 us; speedup 1.0000x reference)
//
#include <hip/hip_runtime.h>
#include <hip/hip_bf16.h>

typedef __attribute__((ext_vector_type(4))) float f32x4;
typedef __attribute__((ext_vector_type(8))) short bf16x8;
typedef __attribute__((ext_vector_type(8))) unsigned short u16x8;

#define QCAP 8256  // compact q buffer row capacity
#define QSTR ((size_t)QCAP * 512)
#define KVB 48  // kv blocks: 6 bm x 8 bn (full-K, hi+lo sequential)

__device__ __forceinline__ unsigned short f2bf(float f) {
  unsigned int u = __builtin_bit_cast(unsigned int, f);
  unsigned int r = (u + 0x7FFFu + ((u >> 16) & 1u)) >> 16;
  return (unsigned short)r;
}
__device__ __forceinline__ float bf2f(unsigned short h) {
  unsigned int u = ((unsigned int)h) << 16;
  return __builtin_bit_cast(float, u);
}

__device__ __forceinline__ void gload_lds16(const void* g, void* l) {
  __builtin_amdgcn_global_load_lds(
      (__attribute__((address_space(1))) unsigned int*)g,
      (__attribute__((address_space(3))) unsigned int*)l, 16, 0, 0);
}

// ---------- single-block gather+scan+build ----------
__global__ __launch_bounds__(1024) void gather_scan(
    const int* __restrict__ mask, int* __restrict__ offs,
    int* __restrict__ glob, int* __restrict__ mcnt, int* __restrict__ mlist) {
  __shared__ int scnt[13];
  __shared__ int so[13];
  int tid = threadIdx.x;
  if (tid < 13) scnt[tid] = 0;
  __syncthreads();
#pragma unroll
  for (int i = 0; i < 8; ++i) {  // pass 1: count
    int g = i * 1024 + tid;
    int m = mask[g];
    atomicAdd(&scnt[m > 0 ? (g >> 11) * 3 + m - 1 : 12], 1);
  }
  __syncthreads();
  if (tid == 0) {
    int s = 0;
#pragma unroll
    for (int i = 0; i < 12; ++i) {
      so[i] = s;
      s += scnt[i];
    }
    so[12] = s;
#pragma unroll
    for (int i = 0; i < 13; ++i) offs[i] = so[i];
    *mcnt = scnt[12];
  }
  __syncthreads();
  if (tid < 13) scnt[tid] = 0;
  __syncthreads();
#pragma unroll
  for (int i = 0; i < 8; ++i) {  // pass 2: place
    int g = i * 1024 + tid;
    int m = mask[g];
    if (m > 0) {
      int bt = (g >> 11) * 3 + m - 1;
      int p = atomicAdd(&scnt[bt], 1);
      glob[so[bt] + p] = g;
    } else {
      int p = atomicAdd(&scnt[12], 1);
      mlist[p] = g;
    }
  }
}

// ---------- fused prep: y-gather-convert + weight transposes + latent ------
__global__ __launch_bounds__(256) void prep_all(
    const float* __restrict__ y, const int* __restrict__ glob,
    const int* __restrict__ offs, unsigned short* __restrict__ ybf,
    const float* __restrict__ Wq, const float* __restrict__ Wvk,
    const float* __restrict__ Wo, const float* __restrict__ latent,
    unsigned short* __restrict__ QTh, unsigned short* __restrict__ VKh,
    unsigned short* __restrict__ VKl, unsigned short* __restrict__ OTh,
    unsigned short* __restrict__ latbf) {
  int bid = blockIdx.x;
  if (bid < 16384) {  // y gather + convert (compact valid rows)
    int p = bid >> 1, half = bid & 1;
    if (p >= offs[12]) return;
    int g = glob[p];
    const float* src = y + (size_t)g * 4096 + half * 2048 + threadIdx.x * 8;
    unsigned short* dst = ybf + (size_t)p * 4096 + half * 2048 + threadIdx.x * 8;
    f32x4 a = *(const f32x4*)src;
    f32x4 b = *(const f32x4*)(src + 4);
    u16x8 o;
#pragma unroll
    for (int j = 0; j < 4; ++j) o[j] = f2bf(a[j]);
#pragma unroll
    for (int j = 0; j < 4; ++j) o[4 + j] = f2bf(b[j]);
    *(u16x8*)dst = o;
    return;
  }
  if (bid >= 22528) {  // latent convert
    long i = ((long)(bid - 22528) * 256 + threadIdx.x) * 8;
    f32x4 a = *(const f32x4*)(latent + i);
    f32x4 b = *(const f32x4*)(latent + i + 4);
    u16x8 o;
#pragma unroll
    for (int j = 0; j < 4; ++j) o[j] = f2bf(a[j]);
#pragma unroll
    for (int j = 0; j < 4; ++j) o[4 + j] = f2bf(b[j]);
    *(u16x8*)(latbf + i) = o;
    return;
  }
  // weight transpose + (W_vk only) hi/lo split
  int wb = bid - 16384;
  __shared__ float tile[32][33];
  const float* W;
  unsigned short *Th, *Tl;
  int K, N, nbx, b;
  if (wb < 2048) {
    W = Wq; Th = QTh; Tl = nullptr; K = 4096; N = 512; nbx = 16; b = wb;
  } else if (wb < 4096) {
    W = Wvk; Th = VKh; Tl = VKl; K = 2048; N = 1024; nbx = 32; b = wb - 2048;
  } else {
    W = Wo; Th = OTh; Tl = nullptr; K = 512; N = 4096; nbx = 128; b = wb - 4096;
  }
  int n0 = (b % nbx) * 32, k0 = (b / nbx) * 32;
  int tx = threadIdx.x & 31, ty = threadIdx.x >> 5;
#pragma unroll
  for (int r = 0; r < 4; ++r)
    tile[ty + 8 * r][tx] = W[(size_t)(k0 + ty + 8 * r) * N + n0 + tx];
  __syncthreads();
#pragma unroll
  for (int r = 0; r < 4; ++r) {
    float f = tile[tx][ty + 8 * r];
    unsigned short hi = f2bf(f);
    size_t o = (size_t)(n0 + ty + 8 * r) * K + k0 + tx;
    Th[o] = hi;
    if (Tl) Tl[o] = f2bf(f - bf2f(hi));
  }
}

#define BM 128
#define BN 128
#define BK 64
#define BUFE (BM * BK + BN * BK)  // shorts per LDS buffer

// ---------- combined kv + q GEMM, 2-phase double-buffered pipeline ----------
// blocks [0,KVB): kv full-K, hi+lo sequential (64 steps), direct scatter.
// blocks [KVB,KVB+512): q, KSL=2 (32 steps), fp32 slices via LDS-reshape.
// Counted vmcnt(8): next tile's 8 gload_lds stay in flight across barriers.
__global__ __launch_bounds__(256) void gemm_dual(
    const unsigned short* __restrict__ latbf, const unsigned short* __restrict__ VKh,
    const unsigned short* __restrict__ VKl, const unsigned short* __restrict__ ybf,
    const unsigned short* __restrict__ QTh, unsigned short* __restrict__ Kh,
    unsigned short* __restrict__ Kl, unsigned short* __restrict__ Vt,
    float* __restrict__ qc, const int* __restrict__ offs) {
  __shared__ unsigned short smem[2 * BUFE + 64];
  float* epi = (float*)smem;  // 32 KB reuse after K-loop

  int tid = threadIdx.x, lane = tid & 63, wid = tid >> 6;
  int wr = wid >> 1, wc = wid & 1;
  bool isKV = blockIdx.x < KVB;
  const unsigned short* Ab;
  const unsigned short* VKhb = nullptr;
  const unsigned short* VKlb = nullptr;
  const unsigned short* Bb = nullptr;
  int K, kbeg, bm, bn, ks = 0, nsteps;
  if (isKV) {
    int sw = (blockIdx.x & 7) * (KVB >> 3) + (blockIdx.x >> 3);  // XCD swizzle
    bm = sw / 8;
    bn = sw % 8;
    Ab = latbf + (size_t)(bm * BM) * 2048;
    VKhb = VKh + (size_t)(bn * BN) * 2048;
    VKlb = VKl + (size_t)(bn * BN) * 2048;
    K = 2048;
    kbeg = 0;
    nsteps = 64;  // 2 passes x 32
  } else {
    int qb = blockIdx.x - KVB;          // 0..511
    int w = (qb & 7) * 64 + (qb >> 3);  // XCD swizzle over 512
    bm = w & 63;                        // bm fastest: dead tiles interleave
    int r = w >> 6;                     // 0..7
    bn = r >> 1;
    ks = r & 1;
    if (bm * BM >= offs[12]) return;  // compacted-away tile (uniform exit)
    Ab = ybf + (size_t)(bm * BM) * 4096;
    Bb = QTh + (size_t)(bn * BN) * 4096;
    K = 4096;
    kbeg = ks * 2048;
    nsteps = 32;
  }

  int fr = lane & 15, fq = lane >> 4;
  int srow = lane >> 3, scol = ((lane & 7) ^ (lane >> 3)) * 8;  // pre-swizzled

  auto stage = [&](int bufsel, int s) {
    int k0;
    const unsigned short* Bbase;
    if (isKV) {
      k0 = (s & 31) * BK;
      Bbase = (s >= 32) ? VKlb : VKhb;
    } else {
      k0 = kbeg + s * BK;
      Bbase = Bb;
    }
    unsigned short* Al = smem + bufsel * BUFE;
    unsigned short* Bl2 = Al + BM * BK;
#pragma unroll
    for (int i = 0; i < 4; ++i) {
      int c = wid * 4 + i;
      size_t go = (size_t)(c * 8 + srow) * K + k0 + scol;
      gload_lds16(Ab + go, &Al[c * 512]);
      gload_lds16(Bbase + go, &Bl2[c * 512]);
    }
  };

  f32x4 acc[4][4];
#pragma unroll
  for (int i = 0; i < 4; ++i)
#pragma unroll
    for (int j = 0; j < 4; ++j) acc[i][j] = (f32x4){0.f, 0.f, 0.f, 0.f};

  stage(0, 0);  // prologue: 8 loads in flight
#pragma unroll 1
  for (int s = 0; s < nsteps; ++s) {
    int cur = s & 1;
    if (s + 1 < nsteps) {
      stage(1 - cur, s + 1);  // issue next tile: 16 in flight
      asm volatile("s_waitcnt vmcnt(8)" ::: "memory");  // drain oldest 8
    } else {
      asm volatile("s_waitcnt vmcnt(0)" ::: "memory");
    }
    __builtin_amdgcn_sched_barrier(0);
    __builtin_amdgcn_s_barrier();
    __builtin_amdgcn_sched_barrier(0);
    const unsigned short* Al = smem + cur * BUFE;
    const unsigned short* Bl2 = Al + BM * BK;
#pragma unroll
    for (int kk = 0; kk < 2; ++kk) {
      int ca = (kk * 32 + fq * 8) ^ ((fr & 7) * 8);  // swizzled read col
      bf16x8 af[4], bf[4];
#pragma unroll
      for (int i = 0; i < 4; ++i) {
        af[i] = *(const bf16x8*)&Al[(wr * 64 + i * 16 + fr) * BK + ca];
        bf[i] = *(const bf16x8*)&Bl2[(wc * 64 + i * 16 + fr) * BK + ca];
      }
#pragma unroll
      for (int mi = 0; mi < 4; ++mi)
#pragma unroll
        for (int ni = 0; ni < 4; ++ni)
          acc[mi][ni] = __builtin_amdgcn_mfma_f32_16x16x32_bf16(
              af[mi], bf[ni], acc[mi][ni], 0, 0, 0);
    }
    __builtin_amdgcn_sched_barrier(0);
    __builtin_amdgcn_s_barrier();  // LDS reads done -> buf reusable
    __builtin_amdgcn_sched_barrier(0);
  }

  if (isKV) {
    // direct scatter: K-half -> Kh/Kl [bt][h][key][d]; V-half -> Vt
#pragma unroll
    for (int mi = 0; mi < 4; ++mi)
#pragma unroll
      for (int ni = 0; ni < 4; ++ni)
#pragma unroll
        for (int r = 0; r < 4; ++r) {
          int row = bm * BM + wr * 64 + mi * 16 + fq * 4 + r;
          int col = bn * BN + wc * 64 + ni * 16 + fr;
          int bt = row >> 6, key = row & 63;
          float v = acc[mi][ni][r];
          if (col < 512) {
            int h = col >> 6, d = col & 63;
            unsigned short hi = f2bf(v);
            size_t o = ((size_t)(bt * 8 + h) * 64 + key) * 64 + d;
            Kh[o] = hi;
            Kl[o] = f2bf(v - bf2f(hi));
          } else {
            int c = col - 512;
            int h = c >> 6, d = c & 63;
            Vt[((size_t)(bt * 8 + h) * 64 + d) * 64 + key] = f2bf(v);
          }
        }
    return;
  }

  // q: LDS-reshape epilogue, 512B-contiguous fp32 slice stores
#pragma unroll 1
  for (int p = 0; p < 2; ++p) {
    __syncthreads();
    if (wr == p) {
#pragma unroll
      for (int mi = 0; mi < 4; ++mi)
#pragma unroll
        for (int ni = 0; ni < 4; ++ni)
#pragma unroll
          for (int r = 0; r < 4; ++r) {
            int lrow = mi * 16 + fq * 4 + r;
            int lcol = wc * 64 + ni * 16 + fr;
            int pc = lcol ^ ((lrow & 7) << 4);
            epi[lrow * 128 + pc] = acc[mi][ni][r];
          }
    }
    __syncthreads();
#pragma unroll
    for (int k = 0; k < 8; ++k) {
      int chunk = k * 256 + tid;
      int lrow = chunk >> 5;
      int c4 = (chunk & 31) * 4;
      int pc4 = c4 ^ ((lrow & 7) << 4);
      f32x4 v = *(f32x4*)&epi[lrow * 128 + pc4];
      int row = bm * BM + p * 64 + lrow;
      *(f32x4*)&qc[(size_t)ks * QSTR + (size_t)row * 512 + bn * BN + c4] = v;
    }
  }
}

// ---------- out-GEMM: 2-phase pipeline, row-scatter, fused zerofill ----------
__global__ __launch_bounds__(256) void gemm_out(
    const unsigned short* __restrict__ A, const unsigned short* __restrict__ Bh,
    float* __restrict__ Cv, const int* __restrict__ glob,
    const int* __restrict__ offs, const int* __restrict__ mcnt,
    const int* __restrict__ mlist, int M, int N, int K) {
  __shared__ unsigned short smem[2 * BUFE + 64];
  float* epi = (float*)smem;

  int tid = threadIdx.x, lane = tid & 63, wid = tid >> 6;
  int wr = wid >> 1, wc = wid & 1;
  int nwg = gridDim.x;
  int w = (blockIdx.x & 7) * (nwg >> 3) + (blockIdx.x >> 3);
  int nTN = N / BN;
  int nBM = M / BM;
  int bm = w % nBM;
  int bn = w / nBM;
  int mv = offs[12];

  if (bm * BM >= mv) {
    // dead block: zero-fill masked output rows
    int bmLive = (mv + BM - 1) / BM;
    int nDead = (nBM - bmLive) * nTN;
    int deadIdx = (bm - bmLive) + bn * (nBM - bmLive);
    int nm = *mcnt;
    f32x4 z = (f32x4){0.f, 0.f, 0.f, 0.f};
    for (int j = deadIdx; j < nm; j += nDead) {
      float* row = Cv + (size_t)mlist[j] * N;
#pragma unroll
      for (int i = 0; i < 4; ++i) *(f32x4*)&row[(i * 256 + tid) * 4] = z;
    }
    return;
  }

  const unsigned short* Ab = A + (size_t)(bm * BM) * K;
  const unsigned short* Bhb = Bh + (size_t)(bn * BN) * K;
  int fr = lane & 15, fq = lane >> 4;
  int srow = lane >> 3, scol = ((lane & 7) ^ (lane >> 3)) * 8;
  int nsteps = K / BK;  // 8

  auto stage = [&](int bufsel, int s) {
    int k0 = s * BK;
    unsigned short* Al = smem + bufsel * BUFE;
    unsigned short* Bl2 = Al + BM * BK;
#pragma unroll
    for (int i = 0; i < 4; ++i) {
      int c = wid * 4 + i;
      size_t go = (size_t)(c * 8 + srow) * K + k0 + scol;
      gload_lds16(Ab + go, &Al[c * 512]);
      gload_lds16(Bhb + go, &Bl2[c * 512]);
    }
  };

  f32x4 acc[4][4];
#pragma unroll
  for (int i = 0; i < 4; ++i)
#pragma unroll
    for (int j = 0; j < 4; ++j) acc[i][j] = (f32x4){0.f, 0.f, 0.f, 0.f};

  stage(0, 0);
#pragma unroll 1
  for (int s = 0; s < nsteps; ++s) {
    int cur = s & 1;
    if (s + 1 < nsteps) {
      stage(1 - cur, s + 1);
      asm volatile("s_waitcnt vmcnt(8)" ::: "memory");
    } else {
      asm volatile("s_waitcnt vmcnt(0)" ::: "memory");
    }
    __builtin_amdgcn_sched_barrier(0);
    __builtin_amdgcn_s_barrier();
    __builtin_amdgcn_sched_barrier(0);
    const unsigned short* Al = smem + cur * BUFE;
    const unsigned short* Bl2 = Al + BM * BK;
#pragma unroll
    for (int kk = 0; kk < 2; ++kk) {
      int ca = (kk * 32 + fq * 8) ^ ((fr & 7) * 8);
      bf16x8 af[4], bf[4];
#pragma unroll
      for (int i = 0; i < 4; ++i) {
        af[i] = *(const bf16x8*)&Al[(wr * 64 + i * 16 + fr) * BK + ca];
        bf[i] = *(const bf16x8*)&Bl2[(wc * 64 + i * 16 + fr) * BK + ca];
      }
#pragma unroll
      for (int mi = 0; mi < 4; ++mi)
#pragma unroll
        for (int ni = 0; ni < 4; ++ni)
          acc[mi][ni] = __builtin_amdgcn_mfma_f32_16x16x32_bf16(
              af[mi], bf[ni], acc[mi][ni], 0, 0, 0);
    }
    __builtin_amdgcn_sched_barrier(0);
    __builtin_amdgcn_s_barrier();
    __builtin_amdgcn_sched_barrier(0);
  }

#pragma unroll 1
  for (int p = 0; p < 2; ++p) {
    __syncthreads();
    if (wr == p) {
#pragma unroll
      for (int mi = 0; mi < 4; ++mi)
#pragma unroll
        for (int ni = 0; ni < 4; ++ni)
#pragma unroll
          for (int r = 0; r < 4; ++r) {
            int lrow = mi * 16 + fq * 4 + r;
            int lcol = wc * 64 + ni * 16 + fr;
            int pc = lcol ^ ((lrow & 7) << 4);
            epi[lrow * 128 + pc] = acc[mi][ni][r];
          }
    }
    __syncthreads();
#pragma unroll
    for (int k = 0; k < 8; ++k) {
      int chunk = k * 256 + tid;
      int lrow = chunk >> 5;
      int c4 = (chunk & 31) * 4;
      int pc4 = c4 ^ ((lrow & 7) << 4);
      f32x4 v = *(f32x4*)&epi[lrow * 128 + pc4];
      int row = bm * BM + p * 64 + lrow;
      if (row < mv)
        *(f32x4*)&Cv[(size_t)glob[row] * N + bn * BN + c4] = v;
    }
  }

  // rare fallback: masked rows exist but no dead blocks
  int bmLive = (mv + BM - 1) / BM;
  if (bmLive == nBM && bm == 0) {
    int nm = *mcnt;
    f32x4 z = (f32x4){0.f, 0.f, 0.f, 0.f};
    for (int j = bn; j < nm; j += nTN) {
      float* row = Cv + (size_t)mlist[j] * N;
#pragma unroll
      for (int i = 0; i < 4; ++i) *(f32x4*)&row[(i * 256 + tid) * 4] = z;
    }
  }
}

// ---------- MFMA attention (compact positions, sums 2 q partials) ----------
__global__ __launch_bounds__(256) void attn5(
    const float* __restrict__ qc, const unsigned short* __restrict__ Kh,
    const unsigned short* __restrict__ Kl, const unsigned short* __restrict__ Vt,
    const int* __restrict__ offs, unsigned short* __restrict__ attnc) {
  __shared__ unsigned short Pl[4][32][72];
  int tid = threadIdx.x, wid = tid >> 6, lane = tid & 63;
  int fr = lane & 15, fq = lane >> 4;
  int bt = blockIdx.x >> 6, rt = blockIdx.x & 63;
  int n = offs[bt + 1] - offs[bt];
  int rbase = rt * 32;
  if (rbase >= n) return;
  int qbase = offs[bt] + rbase;

#pragma unroll 1
  for (int hp = 0; hp < 2; ++hp) {
    int h = wid * 2 + hp;
    const unsigned short* khb = Kh + ((size_t)(bt * 8 + h) * 64) * 64;
    const unsigned short* klb = Kl + ((size_t)(bt * 8 + h) * 64) * 64;
    const unsigned short* vtb = Vt + ((size_t)(bt * 8 + h) * 64) * 64;

    f32x4 sacc[2][4];
#pragma unroll
    for (int i = 0; i < 2; ++i)
#pragma unroll
      for (int j = 0; j < 4; ++j) sacc[i][j] = (f32x4){0.f, 0.f, 0.f, 0.f};

#pragma unroll
    for (int kk = 0; kk < 2; ++kk) {
      bf16x8 qh[2], ql[2];
#pragma unroll
      for (int mi = 0; mi < 2; ++mi) {
        size_t qo = (size_t)(qbase + mi * 16 + fr) * 512 + h * 64 + kk * 32 + fq * 8;
        f32x4 s0 = *(const f32x4*)(qc + qo) + *(const f32x4*)(qc + QSTR + qo);
        f32x4 s1 = *(const f32x4*)(qc + qo + 4) +
                   *(const f32x4*)(qc + QSTR + qo + 4);
        float sv[8];
        *(f32x4*)&sv[0] = s0;
        *(f32x4*)&sv[4] = s1;
#pragma unroll
        for (int j = 0; j < 8; ++j) {
          unsigned short hi = f2bf(sv[j]);
          qh[mi][j] = (short)hi;
          ql[mi][j] = (short)f2bf(sv[j] - bf2f(hi));
        }
      }
#pragma unroll
      for (int ni = 0; ni < 4; ++ni) {
        size_t ko = (size_t)(ni * 16 + fr) * 64 + kk * 32 + fq * 8;
        bf16x8 kh = *(const bf16x8*)(khb + ko);
        bf16x8 kl = *(const bf16x8*)(klb + ko);
#pragma unroll
        for (int mi = 0; mi < 2; ++mi) {
          sacc[mi][ni] = __builtin_amdgcn_mfma_f32_16x16x32_bf16(
              qh[mi], kh, sacc[mi][ni], 0, 0, 0);
          sacc[mi][ni] = __builtin_amdgcn_mfma_f32_16x16x32_bf16(
              qh[mi], kl, sacc[mi][ni], 0, 0, 0);
          sacc[mi][ni] = __builtin_amdgcn_mfma_f32_16x16x32_bf16(
              ql[mi], kh, sacc[mi][ni], 0, 0, 0);
        }
      }
    }

#pragma unroll
    for (int mi = 0; mi < 2; ++mi) {
#pragma unroll
      for (int r = 0; r < 4; ++r) {
        float m = fmaxf(fmaxf(sacc[mi][0][r], sacc[mi][1][r]),
                        fmaxf(sacc[mi][2][r], sacc[mi][3][r]));
#pragma unroll
        for (int o = 1; o < 16; o <<= 1) m = fmaxf(m, __shfl_xor(m, o));
        float e0 = __expf(sacc[mi][0][r] - m);
        float e1 = __expf(sacc[mi][1][r] - m);
        float e2 = __expf(sacc[mi][2][r] - m);
        float e3 = __expf(sacc[mi][3][r] - m);
        float s = e0 + e1 + e2 + e3;
#pragma unroll
        for (int o = 1; o < 16; o <<= 1) s += __shfl_xor(s, o);
        float inv = 1.f / s;
        int row = mi * 16 + fq * 4 + r;
        Pl[wid][row][fr] = f2bf(e0 * inv);
        Pl[wid][row][16 + fr] = f2bf(e1 * inv);
        Pl[wid][row][32 + fr] = f2bf(e2 * inv);
        Pl[wid][row][48 + fr] = f2bf(e3 * inv);
      }
    }

    f32x4 oacc[2][4];
#pragma unroll
    for (int i = 0; i < 2; ++i)
#pragma unroll
      for (int j = 0; j < 4; ++j) oacc[i][j] = (f32x4){0.f, 0.f, 0.f, 0.f};
#pragma unroll
    for (int kk = 0; kk < 2; ++kk) {
      bf16x8 pa[2];
#pragma unroll
      for (int mi = 0; mi < 2; ++mi)
        pa[mi] = *(const bf16x8*)&Pl[wid][mi * 16 + fr][kk * 32 + fq * 8];
#pragma unroll
      for (int ni = 0; ni < 4; ++ni) {
        bf16x8 vb = *(const bf16x8*)(vtb + (size_t)(ni * 16 + fr) * 64 +
                                     kk * 32 + fq * 8);
#pragma unroll
        for (int mi = 0; mi < 2; ++mi)
          oacc[mi][ni] = __builtin_amdgcn_mfma_f32_16x16x32_bf16(
              pa[mi], vb, oacc[mi][ni], 0, 0, 0);
      }
    }

#pragma unroll
    for (int mi = 0; mi < 2; ++mi)
#pragma unroll
      for (int r = 0; r < 4; ++r) {
        int row = mi * 16 + fq * 4 + r;
        if (rbase + row < n) {
          unsigned short* ar = attnc + (size_t)(qbase + row) * 512 + h * 64 + fr;
          ar[0] = f2bf(oacc[mi][0][r]);
          ar[16] = f2bf(oacc[mi][1][r]);
          ar[32] = f2bf(oacc[mi][2][r]);
          ar[48] = f2bf(oacc[mi][3][r]);
        }
      }
  }
}

// ---------- launch ----------
extern "C" void kernel_launch(void* const* d_in, const int* in_sizes, int n_in,
                              void* d_out, int out_size, void* d_ws,
                              size_t ws_size, hipStream_t stream) {
  const float* latent = (const float*)d_in[0];
  const float* y = (const float*)d_in[1];
  const int* mask = (const int*)d_in[2];
  const float* W_vk = (const float*)d_in[3];
  const float* W_q = (const float*)d_in[4];
  const float* W_out = (const float*)d_in[5];
  float* out = (float*)d_out;

  char* ws = (char*)d_ws;
  size_t off = 0;
  auto alloc = [&](size_t bytes) -> void* {
    void* p = ws + off;
    off = (off + bytes + 255) & ~(size_t)255;
    return p;
  };
  unsigned short* WqT_h = (unsigned short*)alloc((size_t)512 * 4096 * 2);
  unsigned short* WvkT_h = (unsigned short*)alloc((size_t)1024 * 2048 * 2);
  unsigned short* WvkT_l = (unsigned short*)alloc((size_t)1024 * 2048 * 2);
  unsigned short* WoT_h = (unsigned short*)alloc((size_t)4096 * 512 * 2);
  unsigned short* ybf = (unsigned short*)alloc((size_t)8192 * 4096 * 2);
  unsigned short* latbf = (unsigned short*)alloc((size_t)768 * 2048 * 2);
  float* qc = (float*)alloc((size_t)2 * QCAP * 512 * 4);  // 2 q slices
  unsigned short* Khb = (unsigned short*)alloc((size_t)768 * 512 * 2);
  unsigned short* Klb = (unsigned short*)alloc((size_t)768 * 512 * 2);
  unsigned short* Vtb = (unsigned short*)alloc((size_t)768 * 512 * 2);
  unsigned short* attnc = (unsigned short*)alloc((size_t)8192 * 512 * 2);
  int* offs = (int*)alloc(13 * 4);
  int* glob = (int*)alloc(8192 * 4);
  int* mcnt = (int*)alloc(4);
  int* mlist = (int*)alloc(8192 * 4);

  // gather + scan + build (single block; no memsets needed)
  gather_scan<<<1, 1024, 0, stream>>>(mask, offs, glob, mcnt, mlist);

  // y gather-convert + weight transposes + latent convert (one dispatch)
  prep_all<<<23296, 256, 0, stream>>>(y, glob, offs, ybf, W_q, W_vk, W_out,
                                      latent, WqT_h, WvkT_h, WvkT_l, WoT_h,
                                      latbf);

  // kv (direct Kh/Kl/Vt) + q partials (2 slices), ONE dispatch, pipelined
  gemm_dual<<<KVB + 512, 256, 0, stream>>>(latbf, WvkT_h, WvkT_l, ybf, WqT_h,
                                           Khb, Klb, Vtb, qc, offs);
  // MFMA attention (sums 2 q partials)
  attn5<<<12 * 64, 256, 0, stream>>>(qc, Khb, Klb, Vtb, offs, attnc);
  // out = attnc[compact,512] @ W_out -> scatter; dead blocks zero-fill
  gemm_out<<<(8192 / BM) * (4096 / BN), 256, 0, stream>>>(
      attnc, WoT_h, out, glob, offs, mcnt, mlist, 8192, 4096, 512);
}

// Round 22
// 211.445 us; speedup vs baseline: 1.2288x; 1.2288x over previous
//
#include <hip/hip_runtime.h>
#include <hip/hip_bf16.h>

typedef __attribute__((ext_vector_type(4))) float f32x4;
typedef __attribute__((ext_vector_type(8))) short bf16x8;
typedef __attribute__((ext_vector_type(8))) unsigned short u16x8;

#define QCAP 8256  // compact q buffer row capacity
#define QSTR ((size_t)QCAP * 512)
#define KVB 48  // kv blocks: 6 bm x 8 bn (full-K, hi+lo sequential)

__device__ __forceinline__ unsigned short f2bf(float f) {
  unsigned int u = __builtin_bit_cast(unsigned int, f);
  unsigned int r = (u + 0x7FFFu + ((u >> 16) & 1u)) >> 16;
  return (unsigned short)r;
}
__device__ __forceinline__ float bf2f(unsigned short h) {
  unsigned int u = ((unsigned int)h) << 16;
  return __builtin_bit_cast(float, u);
}

__device__ __forceinline__ void gload_lds16(const void* g, void* l) {
  __builtin_amdgcn_global_load_lds(
      (__attribute__((address_space(1))) unsigned int*)g,
      (__attribute__((address_space(3))) unsigned int*)l, 16, 0, 0);
}

// ---------- single-block gather+scan+build ----------
__global__ __launch_bounds__(1024) void gather_scan(
    const int* __restrict__ mask, int* __restrict__ offs,
    int* __restrict__ glob, int* __restrict__ mcnt, int* __restrict__ mlist) {
  __shared__ int scnt[13];
  __shared__ int so[13];
  int tid = threadIdx.x;
  if (tid < 13) scnt[tid] = 0;
  __syncthreads();
#pragma unroll
  for (int i = 0; i < 8; ++i) {  // pass 1: count
    int g = i * 1024 + tid;
    int m = mask[g];
    atomicAdd(&scnt[m > 0 ? (g >> 11) * 3 + m - 1 : 12], 1);
  }
  __syncthreads();
  if (tid == 0) {
    int s = 0;
#pragma unroll
    for (int i = 0; i < 12; ++i) {
      so[i] = s;
      s += scnt[i];
    }
    so[12] = s;
#pragma unroll
    for (int i = 0; i < 13; ++i) offs[i] = so[i];
    *mcnt = scnt[12];
  }
  __syncthreads();
  if (tid < 13) scnt[tid] = 0;
  __syncthreads();
#pragma unroll
  for (int i = 0; i < 8; ++i) {  // pass 2: place
    int g = i * 1024 + tid;
    int m = mask[g];
    if (m > 0) {
      int bt = (g >> 11) * 3 + m - 1;
      int p = atomicAdd(&scnt[bt], 1);
      glob[so[bt] + p] = g;
    } else {
      int p = atomicAdd(&scnt[12], 1);
      mlist[p] = g;
    }
  }
}

// ---------- fused prep: y-gather-convert + weight transposes + latent ------
__global__ __launch_bounds__(256) void prep_all(
    const float* __restrict__ y, const int* __restrict__ glob,
    const int* __restrict__ offs, unsigned short* __restrict__ ybf,
    const float* __restrict__ Wq, const float* __restrict__ Wvk,
    const float* __restrict__ Wo, const float* __restrict__ latent,
    unsigned short* __restrict__ QTh, unsigned short* __restrict__ VKh,
    unsigned short* __restrict__ VKl, unsigned short* __restrict__ OTh,
    unsigned short* __restrict__ latbf) {
  int bid = blockIdx.x;
  if (bid < 16384) {  // y gather + convert (compact valid rows)
    int p = bid >> 1, half = bid & 1;
    if (p >= offs[12]) return;
    int g = glob[p];
    const float* src = y + (size_t)g * 4096 + half * 2048 + threadIdx.x * 8;
    unsigned short* dst = ybf + (size_t)p * 4096 + half * 2048 + threadIdx.x * 8;
    f32x4 a = *(const f32x4*)src;
    f32x4 b = *(const f32x4*)(src + 4);
    u16x8 o;
#pragma unroll
    for (int j = 0; j < 4; ++j) o[j] = f2bf(a[j]);
#pragma unroll
    for (int j = 0; j < 4; ++j) o[4 + j] = f2bf(b[j]);
    *(u16x8*)dst = o;
    return;
  }
  if (bid >= 22528) {  // latent convert
    long i = ((long)(bid - 22528) * 256 + threadIdx.x) * 8;
    f32x4 a = *(const f32x4*)(latent + i);
    f32x4 b = *(const f32x4*)(latent + i + 4);
    u16x8 o;
#pragma unroll
    for (int j = 0; j < 4; ++j) o[j] = f2bf(a[j]);
#pragma unroll
    for (int j = 0; j < 4; ++j) o[4 + j] = f2bf(b[j]);
    *(u16x8*)(latbf + i) = o;
    return;
  }
  // weight transpose + (W_vk only) hi/lo split
  int wb = bid - 16384;
  __shared__ float tile[32][33];
  const float* W;
  unsigned short *Th, *Tl;
  int K, N, nbx, b;
  if (wb < 2048) {
    W = Wq; Th = QTh; Tl = nullptr; K = 4096; N = 512; nbx = 16; b = wb;
  } else if (wb < 4096) {
    W = Wvk; Th = VKh; Tl = VKl; K = 2048; N = 1024; nbx = 32; b = wb - 2048;
  } else {
    W = Wo; Th = OTh; Tl = nullptr; K = 512; N = 4096; nbx = 128; b = wb - 4096;
  }
  int n0 = (b % nbx) * 32, k0 = (b / nbx) * 32;
  int tx = threadIdx.x & 31, ty = threadIdx.x >> 5;
#pragma unroll
  for (int r = 0; r < 4; ++r)
    tile[ty + 8 * r][tx] = W[(size_t)(k0 + ty + 8 * r) * N + n0 + tx];
  __syncthreads();
#pragma unroll
  for (int r = 0; r < 4; ++r) {
    float f = tile[tx][ty + 8 * r];
    unsigned short hi = f2bf(f);
    size_t o = (size_t)(n0 + ty + 8 * r) * K + k0 + tx;
    Th[o] = hi;
    if (Tl) Tl[o] = f2bf(f - bf2f(hi));
  }
}

#define BM 128
#define BN 128
#define BK 64

// ---------- combined kv + q GEMM (single dispatch) ----------
// blocks [0,KVB): kv full-K, hi+lo sequential passes into one accumulator,
//                 direct Kh/Kl/Vt scatter epilogue (no partials).
// blocks [KVB,KVB+512): q partials, KSL=2, compact M (bm fastest-varying),
//                 fp32 slices via LDS-reshape epilogue.
__global__ __launch_bounds__(256) void gemm_dual(
    const unsigned short* __restrict__ latbf, const unsigned short* __restrict__ VKh,
    const unsigned short* __restrict__ VKl, const unsigned short* __restrict__ ybf,
    const unsigned short* __restrict__ QTh, unsigned short* __restrict__ Kh,
    unsigned short* __restrict__ Kl, unsigned short* __restrict__ Vt,
    float* __restrict__ qc, const int* __restrict__ offs) {
  __shared__ unsigned short smem[BM * BK + BN * BK + 64];
  unsigned short* Ald = smem;
  unsigned short* Bhld = smem + BM * BK;
  float* epi = (float*)smem;

  int tid = threadIdx.x, lane = tid & 63, wid = tid >> 6;
  int wr = wid >> 1, wc = wid & 1;
  bool isKV = blockIdx.x < KVB;
  const unsigned short* Ab;
  const unsigned short* Bb = nullptr;
  int K, kbeg, kend, bm, bn, ks = 0;
  if (isKV) {
    int sw = (blockIdx.x & 7) * (KVB >> 3) + (blockIdx.x >> 3);  // XCD swizzle
    bm = sw / 8;
    bn = sw % 8;
    Ab = latbf + (size_t)(bm * BM) * 2048;
    K = 2048;
    kbeg = 0;
    kend = 2048;
  } else {
    int qb = blockIdx.x - KVB;          // 0..511
    int w = (qb & 7) * 64 + (qb >> 3);  // XCD swizzle over 512
    bm = w & 63;                        // bm fastest: dead tiles interleave
    int r = w >> 6;                     // 0..7
    bn = r >> 1;
    ks = r & 1;
    if (bm * BM >= offs[12]) return;  // compacted-away tile
    Ab = ybf + (size_t)(bm * BM) * 4096;
    Bb = QTh + (size_t)(bn * BN) * 4096;
    K = 4096;
    kbeg = ks * 2048;
    kend = kbeg + 2048;
  }

  int fr = lane & 15, fq = lane >> 4;
  int srow = lane >> 3, scol = ((lane & 7) ^ (lane >> 3)) * 8;  // pre-swizzled

  f32x4 acc[4][4];
#pragma unroll
  for (int i = 0; i < 4; ++i)
#pragma unroll
    for (int j = 0; j < 4; ++j) acc[i][j] = (f32x4){0.f, 0.f, 0.f, 0.f};

  int npass = isKV ? 2 : 1;
#pragma unroll 1
  for (int pass = 0; pass < npass; ++pass) {
    const unsigned short* Bp =
        isKV ? ((pass ? VKl : VKh) + (size_t)(bn * BN) * 2048) : Bb;
    for (int k0 = kbeg; k0 < kend; k0 += BK) {
#pragma unroll
      for (int i = 0; i < 4; ++i) {
        int c = wid * 4 + i;
        size_t go = (size_t)(c * 8 + srow) * K + k0 + scol;
        gload_lds16(Ab + go, &Ald[c * 512]);
        gload_lds16(Bp + go, &Bhld[c * 512]);
      }
      __syncthreads();
#pragma unroll
      for (int kk = 0; kk < 2; ++kk) {
        int ca = (kk * 32 + fq * 8) ^ ((fr & 7) * 8);  // swizzled read col
        bf16x8 af[4], bf[4];
#pragma unroll
        for (int i = 0; i < 4; ++i) {
          af[i] = *(const bf16x8*)&Ald[(wr * 64 + i * 16 + fr) * BK + ca];
          bf[i] = *(const bf16x8*)&Bhld[(wc * 64 + i * 16 + fr) * BK + ca];
        }
#pragma unroll
        for (int mi = 0; mi < 4; ++mi)
#pragma unroll
          for (int ni = 0; ni < 4; ++ni)
            acc[mi][ni] = __builtin_amdgcn_mfma_f32_16x16x32_bf16(
                af[mi], bf[ni], acc[mi][ni], 0, 0, 0);
      }
      __syncthreads();
    }
  }

  if (isKV) {
    // direct scatter: K-half -> Kh/Kl [bt][h][key][d]; V-half -> Vt [bt][h][d][key]
#pragma unroll
    for (int mi = 0; mi < 4; ++mi)
#pragma unroll
      for (int ni = 0; ni < 4; ++ni)
#pragma unroll
        for (int r = 0; r < 4; ++r) {
          int row = bm * BM + wr * 64 + mi * 16 + fq * 4 + r;
          int col = bn * BN + wc * 64 + ni * 16 + fr;
          int bt = row >> 6, key = row & 63;
          float v = acc[mi][ni][r];
          if (col < 512) {
            int h = col >> 6, d = col & 63;
            unsigned short hi = f2bf(v);
            size_t o = ((size_t)(bt * 8 + h) * 64 + key) * 64 + d;
            Kh[o] = hi;
            Kl[o] = f2bf(v - bf2f(hi));
          } else {
            int c = col - 512;
            int h = c >> 6, d = c & 63;
            Vt[((size_t)(bt * 8 + h) * 64 + d) * 64 + key] = f2bf(v);
          }
        }
    return;
  }

  // q: LDS-reshape epilogue, 512B-contiguous fp32 slice stores
#pragma unroll 1
  for (int p = 0; p < 2; ++p) {
    __syncthreads();
    if (wr == p) {
#pragma unroll
      for (int mi = 0; mi < 4; ++mi)
#pragma unroll
        for (int ni = 0; ni < 4; ++ni)
#pragma unroll
          for (int r = 0; r < 4; ++r) {
            int lrow = mi * 16 + fq * 4 + r;
            int lcol = wc * 64 + ni * 16 + fr;
            int pc = lcol ^ ((lrow & 7) << 4);
            epi[lrow * 128 + pc] = acc[mi][ni][r];
          }
    }
    __syncthreads();
#pragma unroll
    for (int k = 0; k < 8; ++k) {
      int chunk = k * 256 + tid;
      int lrow = chunk >> 5;
      int c4 = (chunk & 31) * 4;
      int pc4 = c4 ^ ((lrow & 7) << 4);
      f32x4 v = *(f32x4*)&epi[lrow * 128 + pc4];
      int row = bm * BM + p * 64 + lrow;
      *(f32x4*)&qc[(size_t)ks * QSTR + (size_t)row * 512 + bn * BN + c4] = v;
    }
  }
}

// ---------- out-GEMM: bf16 single-B, row-scatter, fused zerofill ----------
__global__ __launch_bounds__(256) void gemm_out(
    const unsigned short* __restrict__ A, const unsigned short* __restrict__ Bh,
    float* __restrict__ Cv, const int* __restrict__ glob,
    const int* __restrict__ offs, const int* __restrict__ mcnt,
    const int* __restrict__ mlist, int M, int N, int K) {
  __shared__ unsigned short smem[BM * BK + BN * BK + 64];
  unsigned short* Ald = smem;
  unsigned short* Bhld = smem + BM * BK;
  float* epi = (float*)smem;

  int tid = threadIdx.x, lane = tid & 63, wid = tid >> 6;
  int wr = wid >> 1, wc = wid & 1;
  int nwg = gridDim.x;
  int w = (blockIdx.x & 7) * (nwg >> 3) + (blockIdx.x >> 3);
  int nTN = N / BN;
  int nBM = M / BM;
  int bm = w % nBM;
  int bn = w / nBM;
  int mv = offs[12];

  if (bm * BM >= mv) {
    // dead block: zero-fill masked output rows
    int bmLive = (mv + BM - 1) / BM;
    int nDead = (nBM - bmLive) * nTN;
    int deadIdx = (bm - bmLive) + bn * (nBM - bmLive);
    int nm = *mcnt;
    f32x4 z = (f32x4){0.f, 0.f, 0.f, 0.f};
    for (int j = deadIdx; j < nm; j += nDead) {
      float* row = Cv + (size_t)mlist[j] * N;
#pragma unroll
      for (int i = 0; i < 4; ++i) *(f32x4*)&row[(i * 256 + tid) * 4] = z;
    }
    return;
  }

  const unsigned short* Ab = A + (size_t)(bm * BM) * K;
  const unsigned short* Bhb = Bh + (size_t)(bn * BN) * K;
  int fr = lane & 15, fq = lane >> 4;
  int srow = lane >> 3, scol = ((lane & 7) ^ (lane >> 3)) * 8;

  f32x4 acc[4][4];
#pragma unroll
  for (int i = 0; i < 4; ++i)
#pragma unroll
    for (int j = 0; j < 4; ++j) acc[i][j] = (f32x4){0.f, 0.f, 0.f, 0.f};

  for (int k0 = 0; k0 < K; k0 += BK) {
#pragma unroll
    for (int i = 0; i < 4; ++i) {
      int c = wid * 4 + i;
      size_t go = (size_t)(c * 8 + srow) * K + k0 + scol;
      gload_lds16(Ab + go, &Ald[c * 512]);
      gload_lds16(Bhb + go, &Bhld[c * 512]);
    }
    __syncthreads();
#pragma unroll
    for (int kk = 0; kk < 2; ++kk) {
      int ca = (kk * 32 + fq * 8) ^ ((fr & 7) * 8);
      bf16x8 af[4], bf[4];
#pragma unroll
      for (int i = 0; i < 4; ++i) {
        af[i] = *(const bf16x8*)&Ald[(wr * 64 + i * 16 + fr) * BK + ca];
        bf[i] = *(const bf16x8*)&Bhld[(wc * 64 + i * 16 + fr) * BK + ca];
      }
#pragma unroll
      for (int mi = 0; mi < 4; ++mi)
#pragma unroll
        for (int ni = 0; ni < 4; ++ni)
          acc[mi][ni] = __builtin_amdgcn_mfma_f32_16x16x32_bf16(
              af[mi], bf[ni], acc[mi][ni], 0, 0, 0);
    }
    __syncthreads();
  }

#pragma unroll 1
  for (int p = 0; p < 2; ++p) {
    __syncthreads();
    if (wr == p) {
#pragma unroll
      for (int mi = 0; mi < 4; ++mi)
#pragma unroll
        for (int ni = 0; ni < 4; ++ni)
#pragma unroll
          for (int r = 0; r < 4; ++r) {
            int lrow = mi * 16 + fq * 4 + r;
            int lcol = wc * 64 + ni * 16 + fr;
            int pc = lcol ^ ((lrow & 7) << 4);
            epi[lrow * 128 + pc] = acc[mi][ni][r];
          }
    }
    __syncthreads();
#pragma unroll
    for (int k = 0; k < 8; ++k) {
      int chunk = k * 256 + tid;
      int lrow = chunk >> 5;
      int c4 = (chunk & 31) * 4;
      int pc4 = c4 ^ ((lrow & 7) << 4);
      f32x4 v = *(f32x4*)&epi[lrow * 128 + pc4];
      int row = bm * BM + p * 64 + lrow;
      if (row < mv)
        *(f32x4*)&Cv[(size_t)glob[row] * N + bn * BN + c4] = v;
    }
  }

  // rare fallback: masked rows exist but no dead blocks
  int bmLive = (mv + BM - 1) / BM;
  if (bmLive == nBM && bm == 0) {
    int nm = *mcnt;
    f32x4 z = (f32x4){0.f, 0.f, 0.f, 0.f};
    for (int j = bn; j < nm; j += nTN) {
      float* row = Cv + (size_t)mlist[j] * N;
#pragma unroll
      for (int i = 0; i < 4; ++i) *(f32x4*)&row[(i * 256 + tid) * 4] = z;
    }
  }
}

// ---------- MFMA attention (compact positions, sums 2 q partials) ----------
__global__ __launch_bounds__(256) void attn5(
    const float* __restrict__ qc, const unsigned short* __restrict__ Kh,
    const unsigned short* __restrict__ Kl, const unsigned short* __restrict__ Vt,
    const int* __restrict__ offs, unsigned short* __restrict__ attnc) {
  __shared__ unsigned short Pl[4][32][72];
  int tid = threadIdx.x, wid = tid >> 6, lane = tid & 63;
  int fr = lane & 15, fq = lane >> 4;
  int bt = blockIdx.x >> 6, rt = blockIdx.x & 63;
  int n = offs[bt + 1] - offs[bt];
  int rbase = rt * 32;
  if (rbase >= n) return;
  int qbase = offs[bt] + rbase;

#pragma unroll 1
  for (int hp = 0; hp < 2; ++hp) {
    int h = wid * 2 + hp;
    const unsigned short* khb = Kh + ((size_t)(bt * 8 + h) * 64) * 64;
    const unsigned short* klb = Kl + ((size_t)(bt * 8 + h) * 64) * 64;
    const unsigned short* vtb = Vt + ((size_t)(bt * 8 + h) * 64) * 64;

    f32x4 sacc[2][4];
#pragma unroll
    for (int i = 0; i < 2; ++i)
#pragma unroll
      for (int j = 0; j < 4; ++j) sacc[i][j] = (f32x4){0.f, 0.f, 0.f, 0.f};

#pragma unroll
    for (int kk = 0; kk < 2; ++kk) {
      bf16x8 qh[2], ql[2];
#pragma unroll
      for (int mi = 0; mi < 2; ++mi) {
        size_t qo = (size_t)(qbase + mi * 16 + fr) * 512 + h * 64 + kk * 32 + fq * 8;
        f32x4 s0 = *(const f32x4*)(qc + qo) + *(const f32x4*)(qc + QSTR + qo);
        f32x4 s1 = *(const f32x4*)(qc + qo + 4) +
                   *(const f32x4*)(qc + QSTR + qo + 4);
        float sv[8];
        *(f32x4*)&sv[0] = s0;
        *(f32x4*)&sv[4] = s1;
#pragma unroll
        for (int j = 0; j < 8; ++j) {
          unsigned short hi = f2bf(sv[j]);
          qh[mi][j] = (short)hi;
          ql[mi][j] = (short)f2bf(sv[j] - bf2f(hi));
        }
      }
#pragma unroll
      for (int ni = 0; ni < 4; ++ni) {
        size_t ko = (size_t)(ni * 16 + fr) * 64 + kk * 32 + fq * 8;
        bf16x8 kh = *(const bf16x8*)(khb + ko);
        bf16x8 kl = *(const bf16x8*)(klb + ko);
#pragma unroll
        for (int mi = 0; mi < 2; ++mi) {
          sacc[mi][ni] = __builtin_amdgcn_mfma_f32_16x16x32_bf16(
              qh[mi], kh, sacc[mi][ni], 0, 0, 0);
          sacc[mi][ni] = __builtin_amdgcn_mfma_f32_16x16x32_bf16(
              qh[mi], kl, sacc[mi][ni], 0, 0, 0);
          sacc[mi][ni] = __builtin_amdgcn_mfma_f32_16x16x32_bf16(
              ql[mi], kh, sacc[mi][ni], 0, 0, 0);
        }
      }
    }

#pragma unroll
    for (int mi = 0; mi < 2; ++mi) {
#pragma unroll
      for (int r = 0; r < 4; ++r) {
        float m = fmaxf(fmaxf(sacc[mi][0][r], sacc[mi][1][r]),
                        fmaxf(sacc[mi][2][r], sacc[mi][3][r]));
#pragma unroll
        for (int o = 1; o < 16; o <<= 1) m = fmaxf(m, __shfl_xor(m, o));
        float e0 = __expf(sacc[mi][0][r] - m);
        float e1 = __expf(sacc[mi][1][r] - m);
        float e2 = __expf(sacc[mi][2][r] - m);
        float e3 = __expf(sacc[mi][3][r] - m);
        float s = e0 + e1 + e2 + e3;
#pragma unroll
        for (int o = 1; o < 16; o <<= 1) s += __shfl_xor(s, o);
        float inv = 1.f / s;
        int row = mi * 16 + fq * 4 + r;
        Pl[wid][row][fr] = f2bf(e0 * inv);
        Pl[wid][row][16 + fr] = f2bf(e1 * inv);
        Pl[wid][row][32 + fr] = f2bf(e2 * inv);
        Pl[wid][row][48 + fr] = f2bf(e3 * inv);
      }
    }

    f32x4 oacc[2][4];
#pragma unroll
    for (int i = 0; i < 2; ++i)
#pragma unroll
      for (int j = 0; j < 4; ++j) oacc[i][j] = (f32x4){0.f, 0.f, 0.f, 0.f};
#pragma unroll
    for (int kk = 0; kk < 2; ++kk) {
      bf16x8 pa[2];
#pragma unroll
      for (int mi = 0; mi < 2; ++mi)
        pa[mi] = *(const bf16x8*)&Pl[wid][mi * 16 + fr][kk * 32 + fq * 8];
#pragma unroll
      for (int ni = 0; ni < 4; ++ni) {
        bf16x8 vb = *(const bf16x8*)(vtb + (size_t)(ni * 16 + fr) * 64 +
                                     kk * 32 + fq * 8);
#pragma unroll
        for (int mi = 0; mi < 2; ++mi)
          oacc[mi][ni] = __builtin_amdgcn_mfma_f32_16x16x32_bf16(
              pa[mi], vb, oacc[mi][ni], 0, 0, 0);
      }
    }

#pragma unroll
    for (int mi = 0; mi < 2; ++mi)
#pragma unroll
      for (int r = 0; r < 4; ++r) {
        int row = mi * 16 + fq * 4 + r;
        if (rbase + row < n) {
          unsigned short* ar = attnc + (size_t)(qbase + row) * 512 + h * 64 + fr;
          ar[0] = f2bf(oacc[mi][0][r]);
          ar[16] = f2bf(oacc[mi][1][r]);
          ar[32] = f2bf(oacc[mi][2][r]);
          ar[48] = f2bf(oacc[mi][3][r]);
        }
      }
  }
}

// ---------- launch ----------
extern "C" void kernel_launch(void* const* d_in, const int* in_sizes, int n_in,
                              void* d_out, int out_size, void* d_ws,
                              size_t ws_size, hipStream_t stream) {
  const float* latent = (const float*)d_in[0];
  const float* y = (const float*)d_in[1];
  const int* mask = (const int*)d_in[2];
  const float* W_vk = (const float*)d_in[3];
  const float* W_q = (const float*)d_in[4];
  const float* W_out = (const float*)d_in[5];
  float* out = (float*)d_out;

  char* ws = (char*)d_ws;
  size_t off = 0;
  auto alloc = [&](size_t bytes) -> void* {
    void* p = ws + off;
    off = (off + bytes + 255) & ~(size_t)255;
    return p;
  };
  unsigned short* WqT_h = (unsigned short*)alloc((size_t)512 * 4096 * 2);
  unsigned short* WvkT_h = (unsigned short*)alloc((size_t)1024 * 2048 * 2);
  unsigned short* WvkT_l = (unsigned short*)alloc((size_t)1024 * 2048 * 2);
  unsigned short* WoT_h = (unsigned short*)alloc((size_t)4096 * 512 * 2);
  unsigned short* ybf = (unsigned short*)alloc((size_t)8192 * 4096 * 2);
  unsigned short* latbf = (unsigned short*)alloc((size_t)768 * 2048 * 2);
  float* qc = (float*)alloc((size_t)2 * QCAP * 512 * 4);  // 2 q slices
  unsigned short* Khb = (unsigned short*)alloc((size_t)768 * 512 * 2);
  unsigned short* Klb = (unsigned short*)alloc((size_t)768 * 512 * 2);
  unsigned short* Vtb = (unsigned short*)alloc((size_t)768 * 512 * 2);
  unsigned short* attnc = (unsigned short*)alloc((size_t)8192 * 512 * 2);
  int* offs = (int*)alloc(13 * 4);
  int* glob = (int*)alloc(8192 * 4);
  int* mcnt = (int*)alloc(4);
  int* mlist = (int*)alloc(8192 * 4);

  // gather + scan + build (single block; no memsets needed)
  gather_scan<<<1, 1024, 0, stream>>>(mask, offs, glob, mcnt, mlist);

  // y gather-convert + weight transposes + latent convert (one dispatch)
  prep_all<<<23296, 256, 0, stream>>>(y, glob, offs, ybf, W_q, W_vk, W_out,
                                      latent, WqT_h, WvkT_h, WvkT_l, WoT_h,
                                      latbf);

  // kv (direct Kh/Kl/Vt) + q partials (2 slices), ONE dispatch
  gemm_dual<<<KVB + 512, 256, 0, stream>>>(latbf, WvkT_h, WvkT_l, ybf, WqT_h,
                                           Khb, Klb, Vtb, qc, offs);
  // MFMA attention (sums 2 q partials)
  attn5<<<12 * 64, 256, 0, stream>>>(qc, Khb, Klb, Vtb, offs, attnc);
  // out = attnc[compact,512] @ W_out -> scatter; dead blocks zero-fill
  gemm_out<<<(8192 / BM) * (4096 / BN), 256, 0, stream>>>(
      attnc, WoT_h, out, glob, offs, mcnt, mlist, 8192, 4096, 512);
}